// Round 11
// baseline (86.460 us; speedup 1.0000x reference)
//
#include <hip/hip_runtime.h>
#include <hip/hip_bf16.h>

typedef short short8 __attribute__((ext_vector_type(8)));
typedef unsigned int u32x4 __attribute__((ext_vector_type(4)));
typedef float f32x4 __attribute__((ext_vector_type(4)));
typedef float f32x2 __attribute__((ext_vector_type(2)));

#define SPAT  32768
#define KPROD 27

// tap geometry as compile-time float constants: {ki, kj, kk, 0}
__device__ __constant__ float4 KTAB[KPROD] = {
    {0,0,0,0},{0,0,1,0},{0,0,2,0},{0,1,0,0},{0,1,1,0},{0,1,2,0},{0,2,0,0},{0,2,1,0},{0,2,2,0},
    {1,0,0,0},{1,0,1,0},{1,0,2,0},{1,1,0,0},{1,1,1,0},{1,1,2,0},{1,2,0,0},{1,2,1,0},{1,2,2,0},
    {2,0,0,0},{2,0,1,0},{2,0,2,0},{2,1,0,0},{2,1,1,0},{2,1,2,0},{2,2,0,0},{2,2,1,0},{2,2,2,0}
};

static __device__ __forceinline__ short f2bf(float f) {
    return (short)__bfloat16_as_ushort(__float2bfloat16(f));
}

// quad_perm broadcast: every 4-lane quad gets lane S's value (VALU, no LDS)
template<int S>
static __device__ __forceinline__ int qbcast_i(int x) {
    return __builtin_amdgcn_mov_dpp(x, S * 0x55, 0xF, 0xF, true);
}
template<int S>
static __device__ __forceinline__ float qbcast_f(float x) {
    return __int_as_float(qbcast_i<S>(__float_as_int(x)));
}

// ---- prep 1: x [64][32768] f32 -> xt [32768][64] bf16 (128B rows) ----
__global__ void transpose_x_bf16(const float* __restrict__ x, unsigned short* __restrict__ xt) {
    __shared__ float tile[64][65];
    const int t = threadIdx.x;
    const int s0 = blockIdx.x * 64;
    const int lane = t & 63, grp = t >> 6;
#pragma unroll
    for (int r = 0; r < 16; ++r) {
        int c = grp * 16 + r;
        tile[c][lane] = x[c * SPAT + s0 + lane];
    }
    __syncthreads();
#pragma unroll
    for (int r = 0; r < 16; ++r) {
        int srow = grp * 16 + r;
        xt[(s0 + srow) * 64 + lane] = __bfloat16_as_ushort(__float2bfloat16(tile[lane][srow]));
    }
}

// ---- prep 2: weight [o][c][k] f32 -> A-fragments wf[k][i=ot*2+kb][lane][e] bf16 ----
__global__ void prep_w_frag(const float* __restrict__ w, unsigned short* __restrict__ wt) {
    int idx = blockIdx.x * 256 + threadIdx.x;
    if (idx >= KPROD * 4096) return;
    int k = idx >> 12;
    int fid = idx & 4095;
    int i = fid >> 9;                 // ot*2+kb
    int lane = (fid >> 3) & 63;
    int e = fid & 7;
    int ot = i >> 1, kb = i & 1;
    int o = ot * 16 + (lane & 15);
    int c = kb * 32 + (lane >> 4) * 8 + e;
    wt[idx] = __bfloat16_as_ushort(__float2bfloat16(w[(o * 64 + c) * KPROD + k]));
}

// ---- main: c-split 2 waves, quad-coalesced gathers, DPP meta exchange ----
__global__ __launch_bounds__(128)
void dconv3d_ktab(const unsigned short* __restrict__ xt, const unsigned short* __restrict__ wf,
                  const float* __restrict__ offset, const float* __restrict__ mask,
                  float* __restrict__ out) {
    __shared__ float red[16][65];

    const int t    = threadIdx.x;
    const int wid  = t >> 6;             // channel half
    const int l    = t & 63;
    // MFMA space
    const int pl   = l & 15;
    const int g    = l >> 4;
    // gather space (quad = one 64B line; quad lane gg also owns corner-pair gg)
    const int gp   = l >> 2;
    const int gg   = l & 3;
    const int dhq  = gg >> 1, dwq = gg & 1;
    const int goff = wid * 64 + gg * 16;
    const int bpidx = (pl * 4 + g) * 4;  // MFMA-lane pulls gather-lane 4*pl+g

    // bijective XCD swizzle (2048 % 8 == 0)
    const int nwg = (int)gridDim.x;
    const int cpx = nwg >> 3;
    const int bid = (int)blockIdx.x;
    const int bsw = (bid & 7) * cpx + (bid >> 3);

    const int p_base = bsw * 16;
    const int pos_g = p_base + gp;       // meta/gather space
    const int hog = pos_g >> 10, wog = (pos_g >> 5) & 31, log = pos_g & 31;
    const float fho = (float)(hog - 1), fwo = (float)(wog - 1), flo = (float)(log - 1);
    const char* xbase = (const char*)xt;

    f32x4 acc[4] = {};

    auto load_off = [&](int k) -> f32x4 {
        f32x4 r;
        r.x = offset[(3 * k + 0) * SPAT + pos_g];
        r.y = offset[(3 * k + 1) * SPAT + pos_g];
        r.z = offset[(3 * k + 2) * SPAT + pos_g];
        r.w = mask[k * SPAT + pos_g];
        return r;
    };

    // lane computes its corner-pair (dhq,dwq, dl=0/1) for position gp
    auto compute_meta = [&](int k, f32x4 om, float w01[2], int o01[2]) {
        float4 kt = KTAB[k];             // uniform scalar load (SMEM)
        float chh = om.x + (fho + kt.x);
        float cww = om.y + (fwo + kt.y);
        float cll = om.z + (flo + kt.z);
        float h0f = floorf(chh), w0f = floorf(cww), l0f = floorf(cll);
        float fh = chh - h0f, fw = cww - w0f, fl = cll - l0f;
        int h0 = (int)h0f, w0 = (int)w0f, l0i = (int)l0f;
        int ih = h0 + dhq, iw = w0 + dwq;
        float wh = dhq ? fh : 1.f - fh;
        float ww = dwq ? fw : 1.f - fw;
        float whwm = wh * ww * om.w;
        float w1v = whwm * fl;          // corner dl=1
        float w0v = whwm - w1v;         // corner dl=0
        bool vhw = ((unsigned)ih < 32u) && ((unsigned)iw < 32u);
        bool v0 = vhw && ((unsigned)l0i < 32u);
        bool v1 = vhw && ((unsigned)(l0i + 1) < 32u);
        w01[0] = v0 ? w0v : 0.f;
        w01[1] = v1 ? w1v : 0.f;
        int ihc = min(max(ih, 0), 31), iwc = min(max(iw, 0), 31);
        int l0c = min(max(l0i, 0), 31);
        int l1c = min(max(l0i + 1, 0), 31);   // clamp dl=1 coord independently
        int base2 = (ihc * 32 + iwc) * 32;
        // pre-add my channel-chunk offset so the exchange output is load-ready
        o01[0] = (((base2 + l0c) << 7) + goff);
        o01[1] = (((base2 + l1c) << 7) + goff);
    };

    // DPP exchange: all 8 corners of position gp -> mw/mo[8]
    auto exchange = [&](const float w01[2], const int o01[2], float mwO[8], int moO[8]) {
        mwO[0] = qbcast_f<0>(w01[0]); mwO[1] = qbcast_f<0>(w01[1]);
        mwO[2] = qbcast_f<1>(w01[0]); mwO[3] = qbcast_f<1>(w01[1]);
        mwO[4] = qbcast_f<2>(w01[0]); mwO[5] = qbcast_f<2>(w01[1]);
        mwO[6] = qbcast_f<3>(w01[0]); mwO[7] = qbcast_f<3>(w01[1]);
        moO[0] = qbcast_i<0>(o01[0]); moO[1] = qbcast_i<0>(o01[1]);
        moO[2] = qbcast_i<1>(o01[0]); moO[3] = qbcast_i<1>(o01[1]);
        moO[4] = qbcast_i<2>(o01[0]); moO[5] = qbcast_i<2>(o01[1]);
        moO[6] = qbcast_i<3>(o01[0]); moO[7] = qbcast_i<3>(o01[1]);
    };

    // NOTE: pre-added goff differs per lane (gg), but exchange broadcasts the
    // SOURCE lane's o01 which carries the SOURCE lane's goff — wrong chunk!
    // Fix: goff depends only on (wid, gg); after broadcast from lane S the
    // offset carries chunk S's goff. We need OUR goff. So pre-adding must be
    // of the row-base only; add (goff - src_goff) correction... simpler: keep
    // row-base in o01 and add goff once per j after exchange (8 adds) but
    // fold the +goff into the addressing of the load via pointer pre-offset:
    // xgg = xbase + goff (done once), loads use xgg + mo[j]. Zero per-tap adds.

    const char* xgg = xbase + goff;

    // ---- prologue: meta(0) + gathers(0) issued, off(1) in flight ----
    float mw[8];
    u32x4 q[8];
    {
        f32x4 om0 = load_off(0);
        float w01[2]; int o01[2], mo0[8];
        compute_meta(0, om0, w01, o01);
        // strip the pre-added goff (see note): compute_meta added OUR goff,
        // broadcast would mix chunks — so subtract here and use row-base only.
        o01[0] -= goff; o01[1] -= goff;
        exchange(w01, o01, mw, mo0);
#pragma unroll
        for (int j = 0; j < 8; ++j)
            q[j] = *(const u32x4*)(xgg + mo0[j]);
    }
    f32x4 offA = load_off(1);

#pragma unroll 1
    for (int k = 0; k < KPROD; ++k) {
        // 1. W-frags for this tap first (latency covered by meta+consume)
        short8 wfr[4];
#pragma unroll
        for (int ot = 0; ot < 4; ++ot)
            wfr[ot] = *(const short8*)&wf[((size_t)k * 8 + ot * 2 + wid) * 512 + l * 8];

        // 2. issue off/mask loads for tap k+2 (register prefetch, depth 2)
        f32x4 offB;
        if (k + 2 < KPROD) offB = load_off(k + 2);

        // 3. meta for tap k+1 from registers, DPP-exchange (no LDS, no waits)
        float mwN[8]; int moN[8];
        if (k + 1 < KPROD) {
            float w01[2]; int o01[2];
            compute_meta(k + 1, offA, w01, o01);
            o01[0] -= goff; o01[1] -= goff;   // row-base only (see note)
            exchange(w01, o01, mwN, moN);
        }

        // 4. consume gathers (gather space), weights from registers
        f32x2 v[4] = {};
#pragma unroll
        for (int j = 0; j < 8; ++j) {
            f32x2 w2 = {mw[j], mw[j]};
#pragma unroll
            for (int qd = 0; qd < 4; ++qd) {
                unsigned int a = q[j][qd];
                f32x2 xa = {__uint_as_float(a << 16), __uint_as_float(a & 0xffff0000u)};
                v[qd] = __builtin_elementwise_fma(w2, xa, v[qd]);
            }
        }
        union { short8 s; u32x4 u; } bg;
#pragma unroll
        for (int qd = 0; qd < 4; ++qd) {
            bg.s[2 * qd]     = f2bf(v[qd].x);
            bg.s[2 * qd + 1] = f2bf(v[qd].y);
        }

        // 5. issue gathers for k+1 (q dead; fly under MFMA + next meta)
        if (k + 1 < KPROD) {
#pragma unroll
            for (int j = 0; j < 8; ++j)
                q[j] = *(const u32x4*)(xgg + moN[j]);
        }

        // 6. bridge to MFMA space (pure lane permutation)
        union { u32x4 u; short8 s; } bm;
#pragma unroll
        for (int d = 0; d < 4; ++d)
            bm.u[d] = (unsigned)__builtin_amdgcn_ds_bpermute(bpidx, (int)bg.u[d]);

        // 7. MFMA: 64o x 16p, K=32 (my channel half)
#pragma unroll
        for (int ot = 0; ot < 4; ++ot)
            acc[ot] = __builtin_amdgcn_mfma_f32_16x16x32_bf16(wfr[ot], bm.s, acc[ot], 0, 0, 0);

        // 8. rotate meta weights + off/mask prefetch registers
        if (k + 1 < KPROD) {
#pragma unroll
            for (int j = 0; j < 8; ++j) mw[j] = mwN[j];
        }
        offA = offB;
    }

    // ---- barrier-ordered 2-way reduction (deterministic) ----
    __syncthreads();
    if (wid == 0) {
#pragma unroll
        for (int ot = 0; ot < 4; ++ot)
#pragma unroll
            for (int r = 0; r < 4; ++r)
                red[pl][ot * 16 + g * 4 + r] = acc[ot][r];
    }
    __syncthreads();
    if (wid == 1) {
#pragma unroll
        for (int ot = 0; ot < 4; ++ot)
#pragma unroll
            for (int r = 0; r < 4; ++r)
                red[pl][ot * 16 + g * 4 + r] += acc[ot][r];
    }
    __syncthreads();

    // ---- store: 16-wide p runs per o ----
#pragma unroll
    for (int it = 0; it < 8; ++it) {
        int idx = it * 128 + t;
        int p = idx & 15, o = idx >> 4;
        out[(size_t)o * SPAT + p_base + p] = red[p][o];
    }
}

extern "C" void kernel_launch(void* const* d_in, const int* in_sizes, int n_in,
                              void* d_out, int out_size, void* d_ws, size_t ws_size,
                              hipStream_t stream) {
    const float* x      = (const float*)d_in[0];
    const float* offset = (const float*)d_in[1];
    const float* mask   = (const float*)d_in[2];
    const float* weight = (const float*)d_in[3];
    float* out = (float*)d_out;

    unsigned short* xt  = (unsigned short*)d_ws;                                  // 4 MB
    unsigned short* wtb = (unsigned short*)((char*)d_ws + (size_t)SPAT * 64 * 2); // 216 KB

    hipLaunchKernelGGL(transpose_x_bf16, dim3(SPAT / 64), dim3(256), 0, stream, x, xt);
    hipLaunchKernelGGL(prep_w_frag, dim3((KPROD * 4096 + 255) / 256), dim3(256), 0, stream,
                       weight, wtb);
    hipLaunchKernelGGL(dconv3d_ktab, dim3(SPAT / 16), dim3(128), 0, stream,
                       xt, wtb, offset, mask, out);
}

// Round 12
// 82.856 us; speedup vs baseline: 1.0435x; 1.0435x over previous
//
#include <hip/hip_runtime.h>
#include <hip/hip_bf16.h>

typedef short short8 __attribute__((ext_vector_type(8)));
typedef unsigned int u32x4 __attribute__((ext_vector_type(4)));
typedef float f32x4 __attribute__((ext_vector_type(4)));
typedef float f32x2 __attribute__((ext_vector_type(2)));

#define SPAT  32768
#define KPROD 27

// tap geometry as compile-time float constants: {ki, kj, kk, 0}
__device__ __constant__ float4 KTAB[KPROD] = {
    {0,0,0,0},{0,0,1,0},{0,0,2,0},{0,1,0,0},{0,1,1,0},{0,1,2,0},{0,2,0,0},{0,2,1,0},{0,2,2,0},
    {1,0,0,0},{1,0,1,0},{1,0,2,0},{1,1,0,0},{1,1,1,0},{1,1,2,0},{1,2,0,0},{1,2,1,0},{1,2,2,0},
    {2,0,0,0},{2,0,1,0},{2,0,2,0},{2,1,0,0},{2,1,1,0},{2,1,2,0},{2,2,0,0},{2,2,1,0},{2,2,2,0}
};

static __device__ __forceinline__ short f2bf(float f) {
    return (short)__bfloat16_as_ushort(__float2bfloat16(f));
}

// quad_perm broadcast: every 4-lane quad gets lane S's value (VALU, no LDS)
template<int S>
static __device__ __forceinline__ int qbcast_i(int x) {
    return __builtin_amdgcn_mov_dpp(x, S * 0x55, 0xF, 0xF, true);
}
template<int S>
static __device__ __forceinline__ float qbcast_f(float x) {
    return __int_as_float(qbcast_i<S>(__float_as_int(x)));
}

// ---- prep 1: x [64][32768] f32 -> xt [32768][64] bf16 (128B rows) ----
__global__ void transpose_x_bf16(const float* __restrict__ x, unsigned short* __restrict__ xt) {
    __shared__ float tile[64][65];
    const int t = threadIdx.x;
    const int s0 = blockIdx.x * 64;
    const int lane = t & 63, grp = t >> 6;
#pragma unroll
    for (int r = 0; r < 16; ++r) {
        int c = grp * 16 + r;
        tile[c][lane] = x[c * SPAT + s0 + lane];
    }
    __syncthreads();
#pragma unroll
    for (int r = 0; r < 16; ++r) {
        int srow = grp * 16 + r;
        xt[(s0 + srow) * 64 + lane] = __bfloat16_as_ushort(__float2bfloat16(tile[lane][srow]));
    }
}

// ---- prep 2: weight [o][c][k] f32 -> A-fragments wf[k][i=ot*2+kb][lane][e] bf16 ----
__global__ void prep_w_frag(const float* __restrict__ w, unsigned short* __restrict__ wt) {
    int idx = blockIdx.x * 256 + threadIdx.x;
    if (idx >= KPROD * 4096) return;
    int k = idx >> 12;
    int fid = idx & 4095;
    int i = fid >> 9;                 // ot*2+kb
    int lane = (fid >> 3) & 63;
    int e = fid & 7;
    int ot = i >> 1, kb = i & 1;
    int o = ot * 16 + (lane & 15);
    int c = kb * 32 + (lane >> 4) * 8 + e;
    wt[idx] = __bfloat16_as_ushort(__float2bfloat16(w[(o * 64 + c) * KPROD + k]));
}

// ---- main: c-split 2 waves, quad-coalesced gathers, DPP meta, tap-group split ----
__global__ __launch_bounds__(128)
void dconv3d_ks(const unsigned short* __restrict__ xt, const unsigned short* __restrict__ wf,
                const float* __restrict__ offset, const float* __restrict__ mask,
                float* __restrict__ out0, float* __restrict__ out1, int ngroups) {
    __shared__ float red[16][65];

    const int t    = threadIdx.x;
    const int wid  = t >> 6;             // channel half
    const int l    = t & 63;
    // MFMA space
    const int pl   = l & 15;
    const int g    = l >> 4;
    // gather space (quad = one 64B line; quad lane gg also owns corner-pair gg)
    const int gp   = l >> 2;
    const int gg   = l & 3;
    const int dhq  = gg >> 1, dwq = gg & 1;
    const int goff = wid * 64 + gg * 16;
    const int bpidx = (pl * 4 + g) * 4;  // MFMA-lane pulls gather-lane 4*pl+g

    // tap group: 0 -> taps 0-13 -> out0; 1 -> taps 14-26 -> out1 (partial)
    const int grpid = (ngroups == 2) ? (int)blockIdx.y : 0;
    const int k0 = (ngroups == 2) ? grpid * 14 : 0;
    const int nt = (ngroups == 2) ? (14 - grpid) : KPROD;
    float* outp = (grpid == 0) ? out0 : out1;

    // bijective XCD swizzle (2048 % 8 == 0)
    const int nwg = (int)gridDim.x;
    const int cpx = nwg >> 3;
    const int bid = (int)blockIdx.x;
    const int bsw = (bid & 7) * cpx + (bid >> 3);

    const int p_base = bsw * 16;
    const int pos_g = p_base + gp;       // meta/gather space
    const int hog = pos_g >> 10, wog = (pos_g >> 5) & 31, log = pos_g & 31;
    const float fho = (float)(hog - 1), fwo = (float)(wog - 1), flo = (float)(log - 1);
    const char* xbase = (const char*)xt;
    const char* xgg = xbase + goff;

    f32x4 acc[4] = {};

    auto load_off = [&](int k) -> f32x4 {
        f32x4 r;
        r.x = offset[(3 * k + 0) * SPAT + pos_g];
        r.y = offset[(3 * k + 1) * SPAT + pos_g];
        r.z = offset[(3 * k + 2) * SPAT + pos_g];
        r.w = mask[k * SPAT + pos_g];
        return r;
    };

    // lane computes its corner-pair (dhq,dwq, dl=0/1) for position gp; row-base offsets
    auto compute_meta = [&](int k, f32x4 om, float w01[2], int o01[2]) {
        float4 kt = KTAB[k];             // uniform scalar load (SMEM)
        float chh = om.x + (fho + kt.x);
        float cww = om.y + (fwo + kt.y);
        float cll = om.z + (flo + kt.z);
        float h0f = floorf(chh), w0f = floorf(cww), l0f = floorf(cll);
        float fh = chh - h0f, fw = cww - w0f, fl = cll - l0f;
        int h0 = (int)h0f, w0 = (int)w0f, l0i = (int)l0f;
        int ih = h0 + dhq, iw = w0 + dwq;
        float wh = dhq ? fh : 1.f - fh;
        float ww = dwq ? fw : 1.f - fw;
        float whwm = wh * ww * om.w;
        float w1v = whwm * fl;          // corner dl=1
        float w0v = whwm - w1v;         // corner dl=0
        bool vhw = ((unsigned)ih < 32u) && ((unsigned)iw < 32u);
        bool v0 = vhw && ((unsigned)l0i < 32u);
        bool v1 = vhw && ((unsigned)(l0i + 1) < 32u);
        w01[0] = v0 ? w0v : 0.f;
        w01[1] = v1 ? w1v : 0.f;
        int ihc = min(max(ih, 0), 31), iwc = min(max(iw, 0), 31);
        int l0c = min(max(l0i, 0), 31);
        int l1c = min(max(l0i + 1, 0), 31);   // clamp dl=1 coord independently
        int base2 = (ihc * 32 + iwc) * 32;
        o01[0] = (base2 + l0c) << 7;
        o01[1] = (base2 + l1c) << 7;
    };

    // DPP exchange: all 8 corners of position gp -> mw/mo[8]
    auto exchange = [&](const float w01[2], const int o01[2], float mwO[8], int moO[8]) {
        mwO[0] = qbcast_f<0>(w01[0]); mwO[1] = qbcast_f<0>(w01[1]);
        mwO[2] = qbcast_f<1>(w01[0]); mwO[3] = qbcast_f<1>(w01[1]);
        mwO[4] = qbcast_f<2>(w01[0]); mwO[5] = qbcast_f<2>(w01[1]);
        mwO[6] = qbcast_f<3>(w01[0]); mwO[7] = qbcast_f<3>(w01[1]);
        moO[0] = qbcast_i<0>(o01[0]); moO[1] = qbcast_i<0>(o01[1]);
        moO[2] = qbcast_i<1>(o01[0]); moO[3] = qbcast_i<1>(o01[1]);
        moO[4] = qbcast_i<2>(o01[0]); moO[5] = qbcast_i<2>(o01[1]);
        moO[6] = qbcast_i<3>(o01[0]); moO[7] = qbcast_i<3>(o01[1]);
    };

    // ---- prologue: meta(k0) + gathers(k0) issued, off(k0+1) in flight ----
    float mw[8];
    u32x4 q[8];
    {
        f32x4 om0 = load_off(k0);
        float w01[2]; int o01[2], mo0[8];
        compute_meta(k0, om0, w01, o01);
        exchange(w01, o01, mw, mo0);
#pragma unroll
        for (int j = 0; j < 8; ++j)
            q[j] = *(const u32x4*)(xgg + mo0[j]);
    }
    f32x4 offA = load_off(k0 + 1);

#pragma unroll 1
    for (int kk = 0; kk < nt; ++kk) {
        const int k = k0 + kk;

        // 1. W-frags for this tap first (latency covered by meta+consume)
        short8 wfr[4];
#pragma unroll
        for (int ot = 0; ot < 4; ++ot)
            wfr[ot] = *(const short8*)&wf[((size_t)k * 8 + ot * 2 + wid) * 512 + l * 8];

        // 2. issue off/mask loads for tap k+2 (register prefetch, depth 2)
        f32x4 offB;
        if (kk + 2 < nt) offB = load_off(k + 2);

        // 3. meta for tap k+1 from registers, DPP-exchange (no LDS, no waits)
        float mwN[8]; int moN[8];
        if (kk + 1 < nt) {
            float w01[2]; int o01[2];
            compute_meta(k + 1, offA, w01, o01);
            exchange(w01, o01, mwN, moN);
        }

        // 4. consume gathers (gather space), weights from registers
        f32x2 v[4] = {};
#pragma unroll
        for (int j = 0; j < 8; ++j) {
            f32x2 w2 = {mw[j], mw[j]};
#pragma unroll
            for (int qd = 0; qd < 4; ++qd) {
                unsigned int a = q[j][qd];
                f32x2 xa = {__uint_as_float(a << 16), __uint_as_float(a & 0xffff0000u)};
                v[qd] = __builtin_elementwise_fma(w2, xa, v[qd]);
            }
        }
        union { short8 s; u32x4 u; } bg;
#pragma unroll
        for (int qd = 0; qd < 4; ++qd) {
            bg.s[2 * qd]     = f2bf(v[qd].x);
            bg.s[2 * qd + 1] = f2bf(v[qd].y);
        }

        // 5. issue gathers for k+1 (q dead; fly under MFMA + next meta)
        if (kk + 1 < nt) {
#pragma unroll
            for (int j = 0; j < 8; ++j)
                q[j] = *(const u32x4*)(xgg + moN[j]);
        }

        // 6. bridge to MFMA space (pure lane permutation)
        union { u32x4 u; short8 s; } bm;
#pragma unroll
        for (int d = 0; d < 4; ++d)
            bm.u[d] = (unsigned)__builtin_amdgcn_ds_bpermute(bpidx, (int)bg.u[d]);

        // 7. MFMA: 64o x 16p, K=32 (my channel half)
#pragma unroll
        for (int ot = 0; ot < 4; ++ot)
            acc[ot] = __builtin_amdgcn_mfma_f32_16x16x32_bf16(wfr[ot], bm.s, acc[ot], 0, 0, 0);

        // 8. rotate meta weights + off/mask prefetch registers
        if (kk + 1 < nt) {
#pragma unroll
            for (int j = 0; j < 8; ++j) mw[j] = mwN[j];
        }
        offA = offB;
    }

    // ---- barrier-ordered 2-way reduction (deterministic) ----
    __syncthreads();
    if (wid == 0) {
#pragma unroll
        for (int ot = 0; ot < 4; ++ot)
#pragma unroll
            for (int r = 0; r < 4; ++r)
                red[pl][ot * 16 + g * 4 + r] = acc[ot][r];
    }
    __syncthreads();
    if (wid == 1) {
#pragma unroll
        for (int ot = 0; ot < 4; ++ot)
#pragma unroll
            for (int r = 0; r < 4; ++r)
                red[pl][ot * 16 + g * 4 + r] += acc[ot][r];
    }
    __syncthreads();

    // ---- store: 16-wide p runs per o ----
#pragma unroll
    for (int it = 0; it < 8; ++it) {
        int idx = it * 128 + t;
        int p = idx & 15, o = idx >> 4;
        outp[(size_t)o * SPAT + p_base + p] = red[p][o];
    }
}

// ---- deterministic merge: out += part ----
__global__ void reduce_add(float* __restrict__ out, const float* __restrict__ part) {
    int i = blockIdx.x * 256 + threadIdx.x;     // n4 = 64*SPAT/4 = 524288
    f32x4 a = ((const f32x4*)out)[i];
    f32x4 b = ((const f32x4*)part)[i];
    a.x += b.x; a.y += b.y; a.z += b.z; a.w += b.w;
    ((f32x4*)out)[i] = a;
}

extern "C" void kernel_launch(void* const* d_in, const int* in_sizes, int n_in,
                              void* d_out, int out_size, void* d_ws, size_t ws_size,
                              hipStream_t stream) {
    const float* x      = (const float*)d_in[0];
    const float* offset = (const float*)d_in[1];
    const float* mask   = (const float*)d_in[2];
    const float* weight = (const float*)d_in[3];
    float* out = (float*)d_out;

    const size_t xt_bytes  = (size_t)SPAT * 64 * 2;        // 4 MB
    const size_t wt_bytes  = (size_t)KPROD * 4096 * 2;     // 216 KB
    const size_t prt_bytes = (size_t)64 * SPAT * 4;        // 8 MB

    unsigned short* xt  = (unsigned short*)d_ws;
    unsigned short* wtb = (unsigned short*)((char*)d_ws + xt_bytes);
    float*          prt = (float*)((char*)d_ws + xt_bytes + wt_bytes);

    const bool split = (ws_size >= xt_bytes + wt_bytes + prt_bytes);
    const int ngroups = split ? 2 : 1;

    hipLaunchKernelGGL(transpose_x_bf16, dim3(SPAT / 64), dim3(256), 0, stream, x, xt);
    hipLaunchKernelGGL(prep_w_frag, dim3((KPROD * 4096 + 255) / 256), dim3(256), 0, stream,
                       weight, wtb);
    hipLaunchKernelGGL(dconv3d_ks, dim3(SPAT / 16, ngroups), dim3(128), 0, stream,
                       xt, wtb, offset, mask, out, prt, ngroups);
    if (split)
        hipLaunchKernelGGL(reduce_add, dim3(64 * SPAT / 4 / 256), dim3(256), 0, stream,
                           out, prt);
}